// Round 1
// baseline (195.059 us; speedup 1.0000x reference)
//
#include <hip/hip_runtime.h>
#include <hip/hip_bf16.h>

// N=16, M=2, T=300, V=25, C=64, KT=9, PAD=4. NM=32, skeletons SK=9600, rows=240000.
// Pipeline: prep (weight transforms) -> gcn (bf16 MFMA, y in ws) -> conv (bf16 MFMA GEMM,
// K=576, epilogue BN+ReLU+residual).
//
// Workspace layout (bytes), total ~30.8 MB:
//   Y_OFF   = 0           : y bf16, 9600*25*64 = 15,360,000 elems (30,720,000 B)
//   WC2_OFF = 30,720,000  : conv W bf16, frag layout [(kk*4+quad)][c_out][8] (73,728 B)
//   WGT_OFF = 30,793,728  : gcn W^T bf16 [c][k] (8,192 B)
//   A2P_OFF = 30,801,920  : normalized adjacency bf16, 32x32 zero-padded (2,048 B)
//   SC_OFF  = 30,803,968  : folded BN scale fp32[64]
//   SH_OFF  = 30,804,224  : folded BN shift fp32[64] (absorbs conv_b)

typedef __bf16 bf16x8 __attribute__((ext_vector_type(8)));
typedef __bf16 bf16x4 __attribute__((ext_vector_type(4)));
typedef float  f32x4  __attribute__((ext_vector_type(4)));

#define Y_OFF   0
#define WC2_OFF 30720000
#define WGT_OFF 30793728
#define A2P_OFF 30801920
#define SC_OFF  30803968
#define SH_OFF  30804224

__global__ __launch_bounds__(256) void prep_kernel(
    const float* __restrict__ adj, const float* __restrict__ gcn_w,
    const float* __restrict__ conv_w, const float* __restrict__ conv_b,
    const float* __restrict__ bn_g, const float* __restrict__ bn_b,
    const float* __restrict__ bn_m, const float* __restrict__ bn_v,
    __bf16* __restrict__ wc2, __bf16* __restrict__ wgt,
    __bf16* __restrict__ a2p, float* __restrict__ scale, float* __restrict__ shift) {
  int tid = threadIdx.x;
  // conv weights -> fragment-contiguous layout. K-index kap = kt*64 + ci (kt-major).
  // wc2[((kk*4+quad)*64 + c)*8 + j] = w[c][ci][kt], kap = (kk*4+quad)*8 + j.
  for (int e = blockIdx.x * 256 + tid; e < 36864; e += gridDim.x * 256) {
    int j = e & 7, t1 = e >> 3, c = t1 & 63, g = t1 >> 6;
    int kap = g * 8 + j, kt = kap >> 6, ci = kap & 63;
    wc2[e] = (__bf16)conv_w[(c * 64 + ci) * 9 + kt];
  }
  if (blockIdx.x == 0) {
    for (int e = tid; e < 4096; e += 256) {           // wgt[c][k] = gcn_w[k][c]
      int c = e >> 6, k = e & 63;
      wgt[e] = (__bf16)gcn_w[k * 64 + c];
    }
  } else if (blockIdx.x == 1) {
    for (int e = tid; e < 1024; e += 256) {           // A'' padded to 32x32 with zeros
      int v = e >> 5, u = e & 31;
      float val = 0.f;
      if (v < 25 && u < 25) {
        float dv = 0.f, du = 0.f;
        for (int t = 0; t < 25; ++t) { dv += adj[v * 25 + t]; du += adj[u * 25 + t]; }
        val = rsqrtf(dv) * adj[v * 25 + u] * rsqrtf(du);
      }
      a2p[e] = (__bf16)val;
    }
  } else if (blockIdx.x == 2) {
    if (tid < 64) {
      float sc = bn_g[tid] * rsqrtf(bn_v[tid] + 1e-5f);
      scale[tid] = sc;
      shift[tid] = (conv_b[tid] - bn_m[tid]) * sc + bn_b[tid];
    }
  }
}

// GCN: one skeleton (25 joints) per wave. X1T[c][u] = sum_k WgT[c][k]*h[u][k] (MFMA),
// LDS round-trip, yT[c][v] = sum_u X1T[c][u]*A''[v][u] (A'' symmetric), ReLU+bias.
__global__ __launch_bounds__(256) void gcn_kernel(
    const float* __restrict__ h, const __bf16* __restrict__ wgt_g,
    const __bf16* __restrict__ a2p_g, const float* __restrict__ gcn_b,
    __bf16* __restrict__ y) {
  __shared__ __align__(16) __bf16 wgT[4096];          // [c][k] stride 64
  __shared__ __align__(16) __bf16 a2p[1024];          // [v][u] stride 32
  __shared__ __align__(16) __bf16 hb[4][32 * 72];     // per-wave, [u][k] stride 72 (+16B pad)
  __shared__ __align__(16) __bf16 x1t[4][64 * 40];    // per-wave, [c][u] stride 40
  int tid = threadIdx.x, w = tid >> 6, lane = tid & 63;
  int l15 = lane & 15, quad = lane >> 4;

  { // stage shared weights (vectorized)
    const uint4* src = (const uint4*)wgt_g; uint4* dst = (uint4*)wgT;
    for (int e = tid; e < 512; e += 256) dst[e] = src[e];
    const uint4* s2 = (const uint4*)a2p_g; uint4* d2 = (uint4*)a2p;
    if (tid < 128) d2[tid] = s2[tid];
  }
  __syncthreads();

  int skel = blockIdx.x * 4 + w;                      // 2400*4 = 9600, all valid
  // stage h (fp32 -> bf16), zero pad rows u=25..31
  for (int e = lane; e < 7 * 72; e += 64) hb[w][25 * 72 + e] = (__bf16)0.f;
  for (int it = 0; it < 7; ++it) {
    int u = it * 4 + quad;
    if (u < 25) {
      float4 hv = *(const float4*)&h[(skel * 25 + u) * 64 + l15 * 4];
      bf16x4 b; b[0] = (__bf16)hv.x; b[1] = (__bf16)hv.y; b[2] = (__bf16)hv.z; b[3] = (__bf16)hv.w;
      *(bf16x4*)&hb[w][u * 72 + l15 * 4] = b;
    }
  }
  // GEMM1: M=c(64), N=u(32 padded), K=64
  for (int mt = 0; mt < 4; ++mt)
    for (int nt = 0; nt < 2; ++nt) {
      f32x4 acc = {0.f, 0.f, 0.f, 0.f};
      for (int kk = 0; kk < 2; ++kk) {
        bf16x8 a = *(const bf16x8*)&wgT[(mt * 16 + l15) * 64 + kk * 32 + quad * 8];
        bf16x8 b = *(const bf16x8*)&hb[w][(nt * 16 + l15) * 72 + kk * 32 + quad * 8];
        acc = __builtin_amdgcn_mfma_f32_16x16x32_bf16(a, b, acc, 0, 0, 0);
      }
      int u = nt * 16 + l15, c0 = mt * 16 + quad * 4;   // D: col=lane&15, row=quad*4+reg
      for (int r = 0; r < 4; ++r) x1t[w][(c0 + r) * 40 + u] = (__bf16)acc[r];
    }
  // GEMM2: M=c(64), N=v(32 padded), K=u(32 padded)
  for (int mt = 0; mt < 4; ++mt)
    for (int nt = 0; nt < 2; ++nt) {
      f32x4 acc = {0.f, 0.f, 0.f, 0.f};
      bf16x8 a = *(const bf16x8*)&x1t[w][(mt * 16 + l15) * 40 + quad * 8];
      bf16x8 b = *(const bf16x8*)&a2p[(nt * 16 + l15) * 32 + quad * 8];
      acc = __builtin_amdgcn_mfma_f32_16x16x32_bf16(a, b, acc, 0, 0, 0);
      int v = nt * 16 + l15, c0 = mt * 16 + quad * 4;
      if (v < 25) {
        float4 bias = *(const float4*)&gcn_b[c0];
        bf16x4 o;
        o[0] = (__bf16)fmaxf(acc[0] + bias.x, 0.f);
        o[1] = (__bf16)fmaxf(acc[1] + bias.y, 0.f);
        o[2] = (__bf16)fmaxf(acc[2] + bias.z, 0.f);
        o[3] = (__bf16)fmaxf(acc[3] + bias.w, 0.f);
        *(bf16x4*)&y[skel * 1600 + v * 64 + c0] = o;
      }
    }
}

// Conv GEMM: M=c_out(64), N=t(256/block, 64/wave), K=576 (kt-major: kap=kt*64+ci).
// Each wave owns 64x64 outputs (4x4 MFMA tiles): per kk, 4 A-frags (global, L2-hot)
// and 4 B-frags (LDS) each feed 4 MFMAs. Epilogue: BN-fold + ReLU + residual.
__global__ __launch_bounds__(256) void conv_kernel(
    const __bf16* __restrict__ y, const __bf16* __restrict__ wc2,
    const float* __restrict__ scale, const float* __restrict__ shift,
    const float* __restrict__ h, float* __restrict__ out) {
  __shared__ __align__(16) __bf16 ylds[264 * 72];     // rows t0-4..t0+259, stride 72 (+16B pad)
  int tid = threadIdx.x, w = tid >> 6, lane = tid & 63;
  int l15 = lane & 15, quad = lane >> 4;
  int tb = blockIdx.x, vv = blockIdx.y, nm = blockIdx.z;
  int t0 = tb * 256;
  { // stage y tile: 8 lanes x 16B per row = 128B contiguous per row; zero OOB (conv pad)
    int seg = tid & 7;
    for (int row = tid >> 3; row < 264; row += 32) {
      int tg = t0 - 4 + row;
      uint4 val = {0u, 0u, 0u, 0u};
      if (tg >= 0 && tg < 300)
        val = *(const uint4*)&y[((nm * 300 + tg) * 25 + vv) * 64 + seg * 8];
      *(uint4*)&ylds[row * 72 + seg * 8] = val;
    }
  }
  __syncthreads();
  int wt0 = t0 + w * 64;
  if (wt0 >= 300) return;                             // tail waves: no more barriers, safe
  f32x4 acc[4][4];
  for (int m = 0; m < 4; ++m) for (int n = 0; n < 4; ++n) acc[m][n] = (f32x4){0.f, 0.f, 0.f, 0.f};
  for (int kk = 0; kk < 18; ++kk) {
    bf16x8 a[4];
    const __bf16* wbase = wc2 + ((kk * 4 + quad) * 64) * 8;
    for (int m = 0; m < 4; ++m) a[m] = *(const bf16x8*)&wbase[(m * 16 + l15) * 8];
    int kt = kk >> 1, cib = (kk & 1) * 32 + quad * 8;
    for (int n = 0; n < 4; ++n) {
      bf16x8 b = *(const bf16x8*)&ylds[(w * 64 + n * 16 + l15 + kt) * 72 + cib];
      for (int m = 0; m < 4; ++m)
        acc[m][n] = __builtin_amdgcn_mfma_f32_16x16x32_bf16(a[m], b, acc[m][n], 0, 0, 0);
    }
  }
  for (int n = 0; n < 4; ++n) {
    int tt = wt0 + n * 16 + l15;
    if (tt >= 300) continue;
    for (int m = 0; m < 4; ++m) {
      int c0 = m * 16 + quad * 4;
      int idx = ((nm * 300 + tt) * 25 + vv) * 64 + c0;
      float4 sc = *(const float4*)&scale[c0];
      float4 sh = *(const float4*)&shift[c0];
      float4 hr = *(const float4*)&h[idx];
      float4 o;
      o.x = fmaxf(acc[m][n][0] * sc.x + sh.x, 0.f) + hr.x;
      o.y = fmaxf(acc[m][n][1] * sc.y + sh.y, 0.f) + hr.y;
      o.z = fmaxf(acc[m][n][2] * sc.z + sh.z, 0.f) + hr.z;
      o.w = fmaxf(acc[m][n][3] * sc.w + sh.w, 0.f) + hr.w;
      *(float4*)&out[idx] = o;
    }
  }
}

extern "C" void kernel_launch(void* const* d_in, const int* in_sizes, int n_in,
                              void* d_out, int out_size, void* d_ws, size_t ws_size,
                              hipStream_t stream) {
  const float* h      = (const float*)d_in[0];
  const float* adj    = (const float*)d_in[1];
  const float* gcn_w  = (const float*)d_in[2];
  const float* gcn_b  = (const float*)d_in[3];
  const float* conv_w = (const float*)d_in[4];
  const float* conv_b = (const float*)d_in[5];
  const float* bn_g   = (const float*)d_in[6];
  const float* bn_b   = (const float*)d_in[7];
  const float* bn_m   = (const float*)d_in[8];
  const float* bn_v   = (const float*)d_in[9];
  float* out = (float*)d_out;
  char* ws = (char*)d_ws;

  __bf16* y_ws   = (__bf16*)(ws + Y_OFF);
  __bf16* wc2    = (__bf16*)(ws + WC2_OFF);
  __bf16* wgt    = (__bf16*)(ws + WGT_OFF);
  __bf16* a2p    = (__bf16*)(ws + A2P_OFF);
  float*  scale  = (float*)(ws + SC_OFF);
  float*  shift  = (float*)(ws + SH_OFF);

  prep_kernel<<<64, 256, 0, stream>>>(adj, gcn_w, conv_w, conv_b, bn_g, bn_b, bn_m, bn_v,
                                      wc2, wgt, a2p, scale, shift);
  gcn_kernel<<<2400, 256, 0, stream>>>(h, wgt, a2p, gcn_b, y_ws);
  conv_kernel<<<dim3(2, 25, 32), 256, 0, stream>>>(y_ws, wc2, scale, shift, h, out);
}

// Round 2
// 172.606 us; speedup vs baseline: 1.1301x; 1.1301x over previous
//
#include <hip/hip_runtime.h>
#include <hip/hip_bf16.h>

// N=16, M=2, T=300, V=25, C=64, KT=9, PAD=4. NM=32, skeletons SK=9600, rows=240000.
// prep -> gcn (bf16 MFMA, y in ws, layout [nm][v][t][c]) -> conv (bf16 MFMA GEMM K=576,
// wave-uniform 64c x 64t tiles, wave-private swizzled LDS, BN+ReLU+residual epilogue).
//
// Workspace: Y (30.72 MB) | WC2 (73.7 KB) | WGT (8 KB) | A2P (2 KB) | SC/SH (256 B each)

typedef __bf16 bf16x8 __attribute__((ext_vector_type(8)));
typedef __bf16 bf16x4 __attribute__((ext_vector_type(4)));
typedef float  f32x4  __attribute__((ext_vector_type(4)));

#define Y_OFF   0
#define WC2_OFF 30720000
#define WGT_OFF 30793728
#define A2P_OFF 30801920
#define SC_OFF  30803968
#define SH_OFF  30804224

__global__ __launch_bounds__(256) void prep_kernel(
    const float* __restrict__ adj, const float* __restrict__ gcn_w,
    const float* __restrict__ conv_w, const float* __restrict__ conv_b,
    const float* __restrict__ bn_g, const float* __restrict__ bn_b,
    const float* __restrict__ bn_m, const float* __restrict__ bn_v,
    __bf16* __restrict__ wc2, __bf16* __restrict__ wgt,
    __bf16* __restrict__ a2p, float* __restrict__ scale, float* __restrict__ shift) {
  int tid = threadIdx.x;
  // conv weights -> fragment layout: wc2[((kk*4+quad)*64 + c)*8 + j] = w[c][ci][kt],
  // kap = (kk*4+quad)*8 + j = kt*64 + ci (kt-major K index).
  for (int e = blockIdx.x * 256 + tid; e < 36864; e += gridDim.x * 256) {
    int j = e & 7, t1 = e >> 3, c = t1 & 63, g = t1 >> 6;
    int kap = g * 8 + j, kt = kap >> 6, ci = kap & 63;
    wc2[e] = (__bf16)conv_w[(c * 64 + ci) * 9 + kt];
  }
  if (blockIdx.x == 0) {
    for (int e = tid; e < 4096; e += 256) {           // wgt[c][k] = gcn_w[k][c]
      int c = e >> 6, k = e & 63;
      wgt[e] = (__bf16)gcn_w[k * 64 + c];
    }
  } else if (blockIdx.x == 1) {
    for (int e = tid; e < 1024; e += 256) {           // A'' 32x32 zero-padded
      int v = e >> 5, u = e & 31;
      float val = 0.f;
      if (v < 25 && u < 25) {
        float dv = 0.f, du = 0.f;
        for (int t = 0; t < 25; ++t) { dv += adj[v * 25 + t]; du += adj[u * 25 + t]; }
        val = rsqrtf(dv) * adj[v * 25 + u] * rsqrtf(du);
      }
      a2p[e] = (__bf16)val;
    }
  } else if (blockIdx.x == 2) {
    if (tid < 64) {
      float sc = bn_g[tid] * rsqrtf(bn_v[tid] + 1e-5f);
      scale[tid] = sc;
      shift[tid] = (conv_b[tid] - bn_m[tid]) * sc + bn_b[tid];
    }
  }
}

// GCN: one skeleton (nm,t) per wave. X1T[c][u] = Wg^T . h^T (MFMA), LDS round-trip,
// yT[c][v] = X1T . A''^T, then LDS output stage -> coalesced stores to y[nm][v][t][c].
__global__ __launch_bounds__(256) void gcn_kernel(
    const float* __restrict__ h, const __bf16* __restrict__ wgt_g,
    const __bf16* __restrict__ a2p_g, const float* __restrict__ gcn_b,
    __bf16* __restrict__ y) {
  __shared__ __align__(16) __bf16 wgT[64 * 72];       // [c][k] stride 72 (bank rot 4)
  __shared__ __align__(16) __bf16 a2p[32 * 40];       // [v][u] stride 40 (bank rot 20)
  __shared__ __align__(16) __bf16 hb[4][32 * 72];     // per-wave [u][k] stride 72; reused as
                                                      // ystage [v][c] stride 80 (25*80=2000<2304)
  __shared__ __align__(16) __bf16 x1t[4][64 * 40];    // per-wave [c][u] stride 40
  int tid = threadIdx.x, w = tid >> 6, lane = tid & 63;
  int l15 = lane & 15, quad = lane >> 4;

  { // stage shared weights (vectorized, padded strides)
    for (int e = tid; e < 512; e += 256) {            // wgT: row e>>3, chunk e&7
      uint4 val = ((const uint4*)wgt_g)[e];
      *(uint4*)&wgT[(e >> 3) * 72 + (e & 7) * 8] = val;
    }
    if (tid < 128) {                                  // a2p: row tid>>2, chunk tid&3
      uint4 val = ((const uint4*)a2p_g)[tid];
      *(uint4*)&a2p[(tid >> 2) * 40 + (tid & 3) * 8] = val;
    }
  }
  __syncthreads();

  int skel = blockIdx.x * 4 + w;                      // 2400*4 = 9600, all valid
  int nm = skel / 300, tloc = skel - nm * 300;
  // stage h (fp32 -> bf16), zero-pad rows u=25..31
  for (int e = lane; e < 7 * 72; e += 64) hb[w][25 * 72 + e] = (__bf16)0.f;
  for (int it = 0; it < 7; ++it) {
    int u = it * 4 + quad;
    if (u < 25) {
      float4 hv = *(const float4*)&h[(skel * 25 + u) * 64 + l15 * 4];
      bf16x4 b; b[0] = (__bf16)hv.x; b[1] = (__bf16)hv.y; b[2] = (__bf16)hv.z; b[3] = (__bf16)hv.w;
      *(bf16x4*)&hb[w][u * 72 + l15 * 4] = b;
    }
  }
  // GEMM1: M=c(64), N=u(32 pad), K=64
  for (int mt = 0; mt < 4; ++mt)
    for (int nt = 0; nt < 2; ++nt) {
      f32x4 acc = {0.f, 0.f, 0.f, 0.f};
      for (int kk = 0; kk < 2; ++kk) {
        bf16x8 a = *(const bf16x8*)&wgT[(mt * 16 + l15) * 72 + kk * 32 + quad * 8];
        bf16x8 b = *(const bf16x8*)&hb[w][(nt * 16 + l15) * 72 + kk * 32 + quad * 8];
        acc = __builtin_amdgcn_mfma_f32_16x16x32_bf16(a, b, acc, 0, 0, 0);
      }
      int u = nt * 16 + l15, c0 = mt * 16 + quad * 4;
      for (int r = 0; r < 4; ++r) x1t[w][(c0 + r) * 40 + u] = (__bf16)acc[r];
    }
  // GEMM2: M=c(64), N=v(32 pad), K=u(32 pad); D -> ystage[v][c] stride 80 (in hb)
  for (int mt = 0; mt < 4; ++mt)
    for (int nt = 0; nt < 2; ++nt) {
      f32x4 acc = {0.f, 0.f, 0.f, 0.f};
      bf16x8 a = *(const bf16x8*)&x1t[w][(mt * 16 + l15) * 40 + quad * 8];
      bf16x8 b = *(const bf16x8*)&a2p[(nt * 16 + l15) * 40 + quad * 8];
      acc = __builtin_amdgcn_mfma_f32_16x16x32_bf16(a, b, acc, 0, 0, 0);
      int v = nt * 16 + l15, c0 = mt * 16 + quad * 4;
      if (v < 25) {
        float4 bias = *(const float4*)&gcn_b[c0];
        hb[w][v * 80 + c0 + 0] = (__bf16)fmaxf(acc[0] + bias.x, 0.f);
        hb[w][v * 80 + c0 + 1] = (__bf16)fmaxf(acc[1] + bias.y, 0.f);
        hb[w][v * 80 + c0 + 2] = (__bf16)fmaxf(acc[2] + bias.z, 0.f);
        hb[w][v * 80 + c0 + 3] = (__bf16)fmaxf(acc[3] + bias.w, 0.f);
      }
    }
  // coalesced store: y[((nm*25+v)*300 + tloc)*64 + c], 25 rows x 128 B
  for (int e = lane; e < 200; e += 64) {
    int v = e >> 3, ch = e & 7;
    uint4 val = *(const uint4*)&hb[w][v * 80 + ch * 8];
    *(uint4*)&y[((nm * 25 + v) * 300 + tloc) * 64 + ch * 8] = val;
  }
}

// Conv GEMM: wave-uniform 64c x 64t tiles, K=576. Wave-private swizzled LDS y tile,
// A-frag prefetch. Epilogue: BN-fold + ReLU + fp32 residual.
__global__ __launch_bounds__(256) void conv_kernel(
    const __bf16* __restrict__ y, const __bf16* __restrict__ wc2,
    const float* __restrict__ scale, const float* __restrict__ shift,
    const float* __restrict__ h, float* __restrict__ out) {
  __shared__ __align__(16) __bf16 ylds[4 * 72 * 64];  // per-wave 72 rows x 64c, XOR-swizzled
  int tid = threadIdx.x, w = tid >> 6, lane = tid & 63;
  int l15 = lane & 15, quad = lane >> 4;
  int gid = blockIdx.x * 4 + w;                       // 4000 waves, all identical work
  int ti = gid % 5, r1 = gid / 5;
  int vv = r1 % 25, nm = r1 / 25;
  int t0 = (ti < 4) ? ti * 64 : 236;                  // last tile overlaps 20 rows (benign)

  __bf16* my = &ylds[w * 4608];
  { // stage 72 rows x 128 B contiguous from y[nm][vv][t0-4 .. t0+67][:]
    const __bf16* ybase = &y[((nm * 25 + vv) * 300) * 64];
    uint4 stg[9];
    for (int it = 0; it < 9; ++it) {
      int idx = it * 64 + lane, r = idx >> 3, ch = idx & 7;
      int tg = t0 - 4 + r;
      uint4 val = {0u, 0u, 0u, 0u};
      if (tg >= 0 && tg < 300) val = *(const uint4*)&ybase[tg * 64 + ch * 8];
      stg[it] = val;
    }
    for (int it = 0; it < 9; ++it) {
      int idx = it * 64 + lane, r = idx >> 3, ch = idx & 7;
      *(uint4*)&my[r * 64 + ((ch ^ (r & 7)) * 8)] = stg[it];
    }
  }
  // no __syncthreads: LDS tile is wave-private

  f32x4 acc[4][4];
  for (int m = 0; m < 4; ++m) for (int n = 0; n < 4; ++n) acc[m][n] = (f32x4){0.f, 0.f, 0.f, 0.f};

  bf16x8 a0[4], a1[4];
#define LOADA(dst, kk_) { const __bf16* wb = wc2 + (((kk_) * 4 + quad) * 64) * 8; \
    for (int m = 0; m < 4; ++m) dst[m] = *(const bf16x8*)&wb[(m * 16 + l15) * 8]; }
#define COMPUTE(kk_, areg) { int kt = (kk_) >> 1, chb = ((kk_) & 1) * 4 + quad; \
    for (int n = 0; n < 4; ++n) { \
      int row = n * 16 + l15 + kt; \
      bf16x8 b = *(const bf16x8*)&my[row * 64 + ((chb ^ (row & 7)) * 8)]; \
      for (int m = 0; m < 4; ++m) \
        acc[m][n] = __builtin_amdgcn_mfma_f32_16x16x32_bf16(areg[m], b, acc[m][n], 0, 0, 0); \
    } }
  LOADA(a0, 0)
  for (int kk = 0; kk < 18; kk += 2) {
    LOADA(a1, kk + 1)
    COMPUTE(kk, a0)
    if (kk + 2 < 18) LOADA(a0, kk + 2)
    COMPUTE(kk + 1, a1)
  }
#undef LOADA
#undef COMPUTE

  for (int n = 0; n < 4; ++n) {
    int tt = t0 + n * 16 + l15;                       // always < 300 by tile choice
    for (int m = 0; m < 4; ++m) {
      int c0 = m * 16 + quad * 4;
      int idx = ((nm * 300 + tt) * 25 + vv) * 64 + c0;
      float4 sc = *(const float4*)&scale[c0];
      float4 sh = *(const float4*)&shift[c0];
      float4 hr = *(const float4*)&h[idx];
      float4 o;
      o.x = fmaxf(acc[m][n][0] * sc.x + sh.x, 0.f) + hr.x;
      o.y = fmaxf(acc[m][n][1] * sc.y + sh.y, 0.f) + hr.y;
      o.z = fmaxf(acc[m][n][2] * sc.z + sh.z, 0.f) + hr.z;
      o.w = fmaxf(acc[m][n][3] * sc.w + sh.w, 0.f) + hr.w;
      *(float4*)&out[idx] = o;
    }
  }
}

extern "C" void kernel_launch(void* const* d_in, const int* in_sizes, int n_in,
                              void* d_out, int out_size, void* d_ws, size_t ws_size,
                              hipStream_t stream) {
  const float* h      = (const float*)d_in[0];
  const float* adj    = (const float*)d_in[1];
  const float* gcn_w  = (const float*)d_in[2];
  const float* gcn_b  = (const float*)d_in[3];
  const float* conv_w = (const float*)d_in[4];
  const float* conv_b = (const float*)d_in[5];
  const float* bn_g   = (const float*)d_in[6];
  const float* bn_b   = (const float*)d_in[7];
  const float* bn_m   = (const float*)d_in[8];
  const float* bn_v   = (const float*)d_in[9];
  float* out = (float*)d_out;
  char* ws = (char*)d_ws;

  __bf16* y_ws   = (__bf16*)(ws + Y_OFF);
  __bf16* wc2    = (__bf16*)(ws + WC2_OFF);
  __bf16* wgt    = (__bf16*)(ws + WGT_OFF);
  __bf16* a2p    = (__bf16*)(ws + A2P_OFF);
  float*  scale  = (float*)(ws + SC_OFF);
  float*  shift  = (float*)(ws + SH_OFF);

  prep_kernel<<<64, 256, 0, stream>>>(adj, gcn_w, conv_w, conv_b, bn_g, bn_b, bn_m, bn_v,
                                      wc2, wgt, a2p, scale, shift);
  gcn_kernel<<<2400, 256, 0, stream>>>(h, wgt, a2p, gcn_b, y_ws);
  conv_kernel<<<1000, 256, 0, stream>>>(y_ws, wc2, scale, shift, h, out);
}